// Round 1
// baseline (618.200 us; speedup 1.0000x reference)
//
#include <hip/hip_runtime.h>
#include <hip/hip_bf16.h>
#include <cstdint>
#include <cstddef>

typedef __bf16 bf16;
typedef __bf16 bf16x8 __attribute__((ext_vector_type(8)));
typedef float f32x4 __attribute__((ext_vector_type(4)));

#define NSAMP 16384
#define NF 39

__device__ __forceinline__ void gload_lds16(const void* g, void* lds) {
    __builtin_amdgcn_global_load_lds(
        (const __attribute__((address_space(1))) void*)g,
        (__attribute__((address_space(3))) void*)lds, 16, 0, 0);
}

// ---------------- prep: transpose weights to [N][K] bf16 (pad K0 312->320) ----------------
__global__ __launch_bounds__(256) void prep_weights(
    const float* __restrict__ W0, const float* __restrict__ W1, const float* __restrict__ W2,
    bf16* __restrict__ W0t, bf16* __restrict__ W1t, bf16* __restrict__ W2t) {
    int idx = blockIdx.x * 256 + threadIdx.x;   // grid covers exactly 327680
    if (idx < 512 * 320) {
        int n = idx / 320, kp = idx % 320;
        W0t[idx] = (kp < 312) ? (bf16)W0[kp * 512 + n] : (bf16)0.f;
    } else if (idx < 512 * 320 + 256 * 512) {
        int j = idx - 512 * 320; int n = j / 512, k = j % 512;
        W1t[j] = (bf16)W1[k * 256 + n];
    } else {
        int j = idx - 512 * 320 - 256 * 512; int n = j / 256, k = j % 256;
        W2t[j] = (bf16)W2[k * 128 + n];
    }
}

// ---------------- S matrix: S[i][j] = dot(Vi[i][j%8], Vi[j][i%8]), i<j else 0 ----------------
__global__ __launch_bounds__(256) void compute_S(const float* __restrict__ FM_V, float* __restrict__ S) {
    __shared__ float Vi[NF][64];
    int t = threadIdx.x;
    for (int idx = t; idx < NF * 64; idx += 256) {
        int i = idx >> 6, r = idx & 63;
        Vi[i][r] = FM_V[(size_t)(i * 50000 + i * 1000) * 64 + r];
    }
    __syncthreads();
    for (int idx = t; idx < NF * NF; idx += 256) {
        int i = idx / NF, j = idx % NF;
        float s = 0.f;
        if (i < j) {
            int gj = j & 7 ? j % 8 : 0; gj = j % 8;
            int gi = i % 8;
            #pragma unroll
            for (int e = 0; e < 8; ++e)
                s += Vi[i][gj * 8 + e] * Vi[j][gi * 8 + e];
        }
        S[idx] = s;
    }
}

// ---------------- embedding gather -> h0 bf16 [16384][320] (cols 312..319 zero) ----------------
__global__ __launch_bounds__(256) void gather_h0(
    const int* __restrict__ feat_ids, const float* __restrict__ emb, bf16* __restrict__ h0) {
    int idx = blockIdx.x * 256 + threadIdx.x;   // exactly 16384*40
    int b = idx / 40, i = idx % 40;
    bf16x8 v;
    if (i < NF) {
        int id = feat_ids[b * NF + i];
        const float4* e = (const float4*)(emb + (size_t)id * 8);
        float4 e0 = e[0], e1 = e[1];
        v[0] = (bf16)e0.x; v[1] = (bf16)e0.y; v[2] = (bf16)e0.z; v[3] = (bf16)e0.w;
        v[4] = (bf16)e1.x; v[5] = (bf16)e1.y; v[6] = (bf16)e1.z; v[7] = (bf16)e1.w;
    } else {
        #pragma unroll
        for (int j = 0; j < 8; ++j) v[j] = (bf16)0.f;
    }
    *(bf16x8*)(h0 + (size_t)b * 320 + i * 8) = v;
}

// ---------------- linear + pairwise interaction -> base[b] ----------------
__global__ __launch_bounds__(256) void linear_inter(
    const int* __restrict__ feat_ids, const float* __restrict__ feat_vals,
    const float* __restrict__ FM_W, const float* __restrict__ FM_B,
    const float* __restrict__ S, float* __restrict__ basev) {
    __shared__ float Ss[NF * NF];
    for (int idx = threadIdx.x; idx < NF * NF; idx += 256) Ss[idx] = S[idx];
    __syncthreads();
    int b = blockIdx.x * 256 + threadIdx.x;     // exactly 16384
    float v[NF];
    float lin = 0.f;
    #pragma unroll
    for (int i = 0; i < NF; ++i) {
        int id = feat_ids[b * NF + i];
        float x = feat_vals[b * NF + i];
        v[i] = x;
        lin += FM_W[id] * x;
    }
    float inter = 0.f;
    #pragma unroll
    for (int j = 1; j < NF; ++j) {
        float vj = v[j];
        #pragma unroll
        for (int i = 0; i < j; ++i)
            inter = fmaf(Ss[i * NF + j] * v[i], vj, inter);
    }
    basev[b] = lin + FM_B[0] + inter;
}

// ---------------- MFMA GEMM: A[16384][K] x Bt[N][K] -> relu(.+bias) ----------------
// tile 128x128, BK=64, 4 waves (2x2), each wave 64x64 (4x4 frags of 16x16x32).
// LDS tiles [128 rows][64 cols] bf16, 128B rows, XOR-swizzle slot^=(row&7) (16B slots).
template<int K, int N, int FINAL>
__global__ __launch_bounds__(256, 2) void gemm_k(
    const bf16* __restrict__ A, const bf16* __restrict__ Bt,
    const float* __restrict__ bias,
    const float* __restrict__ outW, const float* __restrict__ outB,
    const float* __restrict__ base, bf16* __restrict__ C, float* __restrict__ out) {
    __shared__ __align__(16) bf16 As[128 * 64];
    __shared__ __align__(16) bf16 Bs[128 * 64];
    __shared__ float red[128];

    const int tid = threadIdx.x;
    const int lane = tid & 63;
    const int wid = tid >> 6;
    const int wm = wid >> 1, wn = wid & 1;
    const int l15 = lane & 15, l4 = lane >> 4;
    const int m0 = blockIdx.x * 128;
    const int n0 = blockIdx.y * 128;

    const int srow = lane >> 3;   // 0..7 within 8-row stripe
    const int slot = lane & 7;    // 16B slot

    // fragment ds_read byte offsets (k0-independent)
    int offA[4][2], offB[4][2];
    #pragma unroll
    for (int m = 0; m < 4; ++m) {
        int ra = wm * 64 + m * 16 + l15;
        int rb = wn * 64 + m * 16 + l15;
        #pragma unroll
        for (int ks = 0; ks < 2; ++ks) {
            offA[m][ks] = ra * 128 + (((ks * 4 + l4) ^ (ra & 7)) << 4);
            offB[m][ks] = rb * 128 + (((ks * 4 + l4) ^ (rb & 7)) << 4);
        }
    }

    f32x4 acc[4][4];
    #pragma unroll
    for (int m = 0; m < 4; ++m)
        #pragma unroll
        for (int n = 0; n < 4; ++n)
            acc[m][n] = (f32x4){0.f, 0.f, 0.f, 0.f};

    for (int k0 = 0; k0 < K; k0 += 64) {
        #pragma unroll
        for (int q = 0; q < 4; ++q) {
            int row = q * 32 + wid * 8 + srow;
            int chunk = slot ^ (row & 7);
            const bf16* ga = A + (size_t)(m0 + row) * K + k0 + chunk * 8;
            const bf16* gb = Bt + (size_t)(n0 + row) * K + k0 + chunk * 8;
            gload_lds16(ga, (void*)&As[(q * 32 + wid * 8) * 64]);
            gload_lds16(gb, (void*)&Bs[(q * 32 + wid * 8) * 64]);
        }
        __syncthreads();
        #pragma unroll
        for (int ks = 0; ks < 2; ++ks) {
            bf16x8 af[4], bfv[4];
            #pragma unroll
            for (int m = 0; m < 4; ++m)
                af[m] = *(const bf16x8*)((const char*)As + offA[m][ks]);
            #pragma unroll
            for (int n = 0; n < 4; ++n)
                bfv[n] = *(const bf16x8*)((const char*)Bs + offB[n][ks]);
            #pragma unroll
            for (int m = 0; m < 4; ++m)
                #pragma unroll
                for (int n = 0; n < 4; ++n)
                    acc[m][n] = __builtin_amdgcn_mfma_f32_16x16x32_bf16(af[m], bfv[n], acc[m][n], 0, 0, 0);
        }
        __syncthreads();
    }

    if (!FINAL) {
        #pragma unroll
        for (int n = 0; n < 4; ++n) {
            int colg = n0 + wn * 64 + n * 16 + l15;
            float bn = bias[colg];
            #pragma unroll
            for (int m = 0; m < 4; ++m) {
                int rowg = m0 + wm * 64 + m * 16 + l4 * 4;
                #pragma unroll
                for (int r = 0; r < 4; ++r) {
                    float v = acc[m][n][r] + bn;
                    v = v > 0.f ? v : 0.f;
                    C[(size_t)(rowg + r) * N + colg] = (bf16)v;
                }
            }
        }
    } else {
        float ps[4][4];
        #pragma unroll
        for (int m = 0; m < 4; ++m)
            #pragma unroll
            for (int r = 0; r < 4; ++r) ps[m][r] = 0.f;
        #pragma unroll
        for (int n = 0; n < 4; ++n) {
            int colg = wn * 64 + n * 16 + l15;    // n0 == 0, N == 128
            float bn = bias[colg];
            float ow = outW[colg];
            #pragma unroll
            for (int m = 0; m < 4; ++m)
                #pragma unroll
                for (int r = 0; r < 4; ++r) {
                    float v = acc[m][n][r] + bn;
                    v = v > 0.f ? v : 0.f;
                    ps[m][r] = fmaf(v, ow, ps[m][r]);
                }
        }
        #pragma unroll
        for (int m = 0; m < 4; ++m)
            #pragma unroll
            for (int r = 0; r < 4; ++r) {
                float s = ps[m][r];
                s += __shfl_xor(s, 1);
                s += __shfl_xor(s, 2);
                s += __shfl_xor(s, 4);
                s += __shfl_xor(s, 8);
                ps[m][r] = s;
            }
        if (tid < 128) red[tid] = 0.f;
        __syncthreads();
        if (l15 == 0) {
            #pragma unroll
            for (int m = 0; m < 4; ++m)
                #pragma unroll
                for (int r = 0; r < 4; ++r)
                    atomicAdd(&red[wm * 64 + m * 16 + l4 * 4 + r], ps[m][r]);
        }
        __syncthreads();
        if (tid < 128) {
            int rowg = m0 + tid;
            float x = base[rowg] + red[tid] + outB[0];
            out[rowg] = 1.f / (1.f + expf(-x));
        }
    }
}

extern "C" void kernel_launch(void* const* d_in, const int* in_sizes, int n_in,
                              void* d_out, int out_size, void* d_ws, size_t ws_size,
                              hipStream_t stream) {
    const int*   feat_ids  = (const int*)d_in[0];
    const float* feat_vals = (const float*)d_in[1];
    const float* FM_W      = (const float*)d_in[2];
    const float* FM_V      = (const float*)d_in[3];
    const float* FM_B      = (const float*)d_in[4];
    const float* emb       = (const float*)d_in[5];
    const float* W0        = (const float*)d_in[6];
    const float* b0        = (const float*)d_in[7];
    const float* W1        = (const float*)d_in[8];
    const float* b1        = (const float*)d_in[9];
    const float* W2        = (const float*)d_in[10];
    const float* b2        = (const float*)d_in[11];
    const float* outW      = (const float*)d_in[12];
    const float* outB      = (const float*)d_in[13];
    float* out = (float*)d_out;
    char* ws = (char*)d_ws;

    float* S    = (float*)(ws);                                  // 8 KB
    float* base = (float*)(ws + 8192);                           // 64 KB
    bf16*  h0   = (bf16*)(ws + 73728);                           // 16384*320*2 = 10.5 MB
    bf16*  h1   = (bf16*)(ws + 73728 + 10485760);                // 16384*512*2 = 16.8 MB
    bf16*  W0t  = (bf16*)(ws + 73728 + 10485760 + 16777216);     // 512*320*2
    bf16*  W1t  = W0t + 512 * 320;                               // 256*512*2
    bf16*  W2t  = W1t + 256 * 512;                               // 128*256*2
    bf16*  h2   = h0;                                            // reuse h0 (dead after GEMM1)

    prep_weights<<<1280, 256, 0, stream>>>(W0, W1, W2, W0t, W1t, W2t);
    compute_S<<<1, 256, 0, stream>>>(FM_V, S);
    gather_h0<<<(NSAMP * 40) / 256, 256, 0, stream>>>(feat_ids, emb, h0);
    linear_inter<<<NSAMP / 256, 256, 0, stream>>>(feat_ids, feat_vals, FM_W, FM_B, S, base);

    gemm_k<320, 512, 0><<<dim3(128, 4), 256, 0, stream>>>(h0, W0t, b0, nullptr, nullptr, nullptr, h1, nullptr);
    gemm_k<512, 256, 0><<<dim3(128, 2), 256, 0, stream>>>(h1, W1t, b1, nullptr, nullptr, nullptr, h2, nullptr);
    gemm_k<256, 128, 1><<<dim3(128, 1), 256, 0, stream>>>(h2, W2t, b2, outW, outB, base, nullptr, out);
}